// Round 5
// baseline (185.536 us; speedup 1.0000x reference)
//
#include <hip/hip_runtime.h>
#include <hip/hip_bf16.h>

#define NB 4
#define NH 8
#define NPX 1024
#define HD 64
#define CDIM 512
#define M_ROWS 4096
#define PS 64
#define S2 16

typedef __attribute__((ext_vector_type(8))) short bf16x8;
typedef __attribute__((ext_vector_type(4))) short bf16x4;
typedef __attribute__((ext_vector_type(4))) float f32x4;

typedef const __attribute__((address_space(1))) unsigned int* gptr_t;
typedef __attribute__((address_space(3))) unsigned int* lptr_t;

static __device__ __forceinline__ short f2bf(float f) {
    __hip_bfloat16 h = __float2bfloat16(f);
    return *reinterpret_cast<short*>(&h);
}

// ---------------- convert: fp32 -> bf16 (x_l, x_s) and transposed bf16 weights ----------------
__global__ void convert_k(const float* __restrict__ xs, const float* __restrict__ xl,
                          const float* __restrict__ Wq, const float* __restrict__ Wk,
                          const float* __restrict__ Wv,
                          short* __restrict__ xl_bf, short* __restrict__ xs_bf,
                          short* __restrict__ WT /* [3][512*512], row=n col=k */) {
    int i = blockIdx.x * blockDim.x + threadIdx.x;   // 0 .. 786431
    if (i < 524288) {
        float4 a = ((const float4*)xl)[i];
        float4 b = ((const float4*)xs)[i];
        short4 oa = make_short4(f2bf(a.x), f2bf(a.y), f2bf(a.z), f2bf(a.w));
        short4 ob = make_short4(f2bf(b.x), f2bf(b.y), f2bf(b.z), f2bf(b.w));
        ((short4*)xl_bf)[i] = oa;
        ((short4*)xs_bf)[i] = ob;
    }
    if (i < 786432) {
        int which = i >> 18;
        int j = i & 262143;
        int n = j >> 9, k = j & 511;
        const float* W = which == 0 ? Wq : (which == 1 ? Wk : Wv);
        WT[i] = f2bf(W[k * 512 + n]);
    }
}

// ---------------- projection GEMM: out[z] = A[z] @ W[z] + b[z], bf16 out ----------------
__global__ __launch_bounds__(256, 2) void proj_gemm(
    const short* __restrict__ xl_bf, const short* __restrict__ xs_bf,
    const short* __restrict__ WT, const float* __restrict__ bq,
    const float* __restrict__ bk, const float* __restrict__ bv,
    short* __restrict__ qkv) {
    __shared__ __attribute__((aligned(16))) short A_lds[128 * 32];
    __shared__ __attribute__((aligned(16))) short B_lds[64 * 32];
    const int z = blockIdx.z;
    const int m0 = blockIdx.x * 128;
    const int n0 = blockIdx.y * 64;
    const short* A = (z == 0) ? xl_bf : xs_bf;
    const short* WTz = WT + z * 262144;
    const float* bias = (z == 0) ? bq : ((z == 1) ? bk : bv);
    short* out = qkv + (size_t)z * M_ROWS * CDIM;
    const int t = threadIdx.x, w = t >> 6, lane = t & 63;
    const int lr = lane & 15, g = lane >> 4;

    f32x4 acc[2][4] = {};
    for (int kt = 0; kt < 16; ++kt) {
        const int k0 = kt * 32;
#pragma unroll
        for (int r = 0; r < 2; ++r) {
            int c = r * 256 + w * 64 + lane;
            const short* src = A + (size_t)(m0 + (c >> 2)) * CDIM + k0 + (c & 3) * 8;
            __builtin_amdgcn_global_load_lds((gptr_t)src,
                (lptr_t)(A_lds + (size_t)(r * 256 + w * 64) * 8), 16, 0, 0);
        }
        {
            int c = w * 64 + lane;
            const short* src = WTz + (size_t)(n0 + (c >> 2)) * CDIM + k0 + (c & 3) * 8;
            __builtin_amdgcn_global_load_lds((gptr_t)src,
                (lptr_t)(B_lds + (size_t)(w * 64) * 8), 16, 0, 0);
        }
        __syncthreads();
        bf16x8 afr[2], bfr[4];
#pragma unroll
        for (int mt = 0; mt < 2; ++mt)
            afr[mt] = *(const bf16x8*)(A_lds + (w * 32 + mt * 16 + lr) * 32 + g * 8);
#pragma unroll
        for (int nt = 0; nt < 4; ++nt)
            bfr[nt] = *(const bf16x8*)(B_lds + (nt * 16 + lr) * 32 + g * 8);
#pragma unroll
        for (int mt = 0; mt < 2; ++mt)
#pragma unroll
            for (int nt = 0; nt < 4; ++nt)
                acc[mt][nt] = __builtin_amdgcn_mfma_f32_16x16x32_bf16(
                    afr[mt], bfr[nt], acc[mt][nt], 0, 0, 0);
        __syncthreads();
    }
#pragma unroll
    for (int mt = 0; mt < 2; ++mt) {
#pragma unroll
        for (int nt = 0; nt < 4; ++nt) {
            int col = n0 + nt * 16 + lr;
            float bv_ = bias[col];
            int row0 = m0 + w * 32 + mt * 16 + g * 4;
#pragma unroll
            for (int r = 0; r < 4; ++r)
                out[(size_t)(row0 + r) * CDIM + col] = f2bf(acc[mt][nt][r] + bv_);
        }
    }
}

// ---------------- V transpose to patch-major: vTp[bh][p][d][s] ----------------
__global__ void v_trans(const short* __restrict__ v_bf, short* __restrict__ vTp) {
    __shared__ __attribute__((aligned(16))) short lds[16 * 512];
    const int blk = blockIdx.x;
    const int b = blk >> 6, p = blk & 63;
    const int py = p >> 3, px = p & 7;
    const int t = threadIdx.x;
#pragma unroll
    for (int r = 0; r < 4; ++r) {
        int ci = r * 256 + t;
        int s = ci >> 6, c8 = (ci & 63) * 8;
        int n = py * 128 + (s >> 2) * 32 + px * 4 + (s & 3);
        *(bf16x8*)(lds + s * 512 + c8) =
            *(const bf16x8*)(v_bf + (size_t)(b * NPX + n) * CDIM + c8);
    }
    __syncthreads();
    const int h = t >> 5, d0 = (t & 31) * 2;
#pragma unroll
    for (int dd = 0; dd < 2; ++dd) {
        int d = d0 + dd;
        short tmp[16];
#pragma unroll
        for (int s = 0; s < 16; ++s) tmp[s] = lds[s * 512 + h * 64 + d];
        short* dst = vTp + ((size_t)((b * 8 + h) * PS + p) * HD + d) * S2;
        *(bf16x8*)(dst) = *(const bf16x8*)(tmp);
        *(bf16x8*)(dst + 8) = *(const bf16x8*)(tmp + 8);
    }
}

// ---------------- fused windowed cross-attention v3 ----------------
// Wave owns 64 queries (4 qtiles, Q persistent in regs) x 8 patches.
// No LDS, no barriers. grid 1024 blocks (XCD-bijective), 4 waves/block.
// Per patch per wave: 6 global loads (4KB), 8+16 MFMA, 4 softmaxes, 16KB nt stores.
__global__ __launch_bounds__(256, 3) void attn_k(
    const short* __restrict__ q_bf, const short* __restrict__ k_bf,
    const short* __restrict__ vTp, float* __restrict__ out) {
    const int bid = blockIdx.x;
    const int wid = ((bid & 7) << 7) | (bid >> 3);     // bijective: 1024 % 8 == 0
    const int bh = wid >> 5;
    const int b = bh >> 3, h = bh & 7;
    const int rem = wid & 31;
    const int qblk = rem >> 3, pgrp = rem & 7;
    const int t = threadIdx.x, w = t >> 6, lane = t & 63;
    const int lr = lane & 15, g = lane >> 4;
    const int l0 = (qblk * 4 + w) * 64;                // 64 queries per wave

    // Q fragments (persist): B-operand col=lr, k-slot(g,i) = half*32 + g*8 + i
    bf16x8 qfr[4][2];
#pragma unroll
    for (int j = 0; j < 4; ++j) {
        const short* qrow = q_bf + (size_t)(b * NPX + l0 + j * 16 + lr) * CDIM + h * HD;
        qfr[j][0] = *(const bf16x8*)(qrow + g * 8);
        qfr[j][1] = *(const bf16x8*)(qrow + 32 + g * 8);
    }
    const int krow_off = (lr >> 2) * 32 + (lr & 3);
    const short* kbase = k_bf + (size_t)(b * NPX) * CDIM + h * HD + g * 8;
    const short* vbase = vTp + ((size_t)(bh * PS) * HD + lr) * S2 + g * 4;
    float* outbh = out + (size_t)bh * PS * NPX * HD;
    const int p0 = pgrp * 8;

    bf16x8 kf[2][2];
    bf16x4 vf[2][4];
    auto loadp = [&](int p, int buf) {
        int py = p >> 3, px = p & 7;
        int n = py * 128 + px * 4 + krow_off;
        const short* kr = kbase + (size_t)n * CDIM;
        kf[buf][0] = *(const bf16x8*)kr;
        kf[buf][1] = *(const bf16x8*)(kr + 32);
        const short* vr = vbase + (size_t)p * HD * S2;
#pragma unroll
        for (int dt = 0; dt < 4; ++dt)
            vf[buf][dt] = *(const bf16x4*)(vr + dt * 16 * S2);
    };
    loadp(p0, 0);
#pragma unroll
    for (int pi = 0; pi < 8; ++pi) {
        const int buf = pi & 1;
        if (pi < 7) loadp(p0 + pi + 1, buf ^ 1);
        float* opp = outbh + (size_t)(p0 + pi) * NPX * HD;
#pragma unroll
        for (int j = 0; j < 4; ++j) {
            // S^T = mfma(K, Q): lane holds S^T[s=4g+r][l = l0 + j*16 + lr]
            f32x4 s_acc = {};
            s_acc = __builtin_amdgcn_mfma_f32_16x16x32_bf16(kf[buf][0], qfr[j][0], s_acc, 0, 0, 0);
            s_acc = __builtin_amdgcn_mfma_f32_16x16x32_bf16(kf[buf][1], qfr[j][1], s_acc, 0, 0, 0);
            float sv[4];
            float m = -1e30f;
#pragma unroll
            for (int r = 0; r < 4; ++r) { sv[r] = s_acc[r] * 0.125f; m = fmaxf(m, sv[r]); }
            m = fmaxf(m, __shfl_xor(m, 16));
            m = fmaxf(m, __shfl_xor(m, 32));
            float pv[4]; float sum = 0.f;
#pragma unroll
            for (int r = 0; r < 4; ++r) { pv[r] = __expf(sv[r] - m); sum += pv[r]; }
            sum += __shfl_xor(sum, 16);
            sum += __shfl_xor(sum, 32);
            float rs = 1.f / sum;
            bf16x8 pfr = { f2bf(pv[0] * rs), f2bf(pv[1] * rs), f2bf(pv[2] * rs), f2bf(pv[3] * rs),
                           0, 0, 0, 0 };
            // PV: out^T[d][l] = sum_s V^T[d][s] * P^T[s][l]
            f32x4 oacc[4];
#pragma unroll
            for (int dt = 0; dt < 4; ++dt) {
                bf16x8 vfr = { vf[buf][dt][0], vf[buf][dt][1], vf[buf][dt][2], vf[buf][dt][3],
                               0, 0, 0, 0 };
                f32x4 zero = {};
                oacc[dt] = __builtin_amdgcn_mfma_f32_16x16x32_bf16(vfr, pfr, zero, 0, 0, 0);
            }
            float* op = opp + (size_t)(l0 + j * 16 + lr) * HD;
#pragma unroll
            for (int dt = 0; dt < 4; ++dt)
                __builtin_nontemporal_store(oacc[dt], (f32x4*)(op + dt * 16 + g * 4));
        }
    }
}

extern "C" void kernel_launch(void* const* d_in, const int* in_sizes, int n_in,
                              void* d_out, int out_size, void* d_ws, size_t ws_size,
                              hipStream_t stream) {
    const float* x_s = (const float*)d_in[0];
    const float* x_l = (const float*)d_in[1];
    const float* Wq  = (const float*)d_in[2];
    const float* bq  = (const float*)d_in[3];
    const float* Wk  = (const float*)d_in[4];
    const float* bk  = (const float*)d_in[5];
    const float* Wv  = (const float*)d_in[6];
    const float* bv  = (const float*)d_in[7];
    float* out = (float*)d_out;
    char* ws = (char*)d_ws;

    short* xl_bf = (short*)(ws);                    // 4 MiB
    short* xs_bf = (short*)(ws + 4194304);          // 4 MiB
    short* WT    = (short*)(ws + 8388608);          // 1.5 MiB
    short* qkv   = (short*)(ws + 9961472);          // 12 MiB
    short* q_bf = qkv;
    short* k_bf = qkv + 2097152;
    short* v_bf = qkv + 4194304;
    short* vTp  = (short*)(ws + 22544384);          // 4 MiB patch-major V^T

    convert_k<<<3072, 256, 0, stream>>>(x_s, x_l, Wq, Wk, Wv, xl_bf, xs_bf, WT);
    proj_gemm<<<dim3(32, 8, 3), 256, 0, stream>>>(xl_bf, xs_bf, WT, bq, bk, bv, qkv);
    v_trans<<<256, 256, 0, stream>>>(v_bf, vTp);
    attn_k<<<1024, 256, 0, stream>>>(q_bf, k_bf, vTp, out);
}

// Round 7
// 170.563 us; speedup vs baseline: 1.0878x; 1.0878x over previous
//
#include <hip/hip_runtime.h>
#include <hip/hip_bf16.h>

#define NB 4
#define NH 8
#define NPX 1024
#define HD 64
#define CDIM 512
#define M_ROWS 4096
#define PS 64
#define S2 16

typedef __attribute__((ext_vector_type(8))) short bf16x8;
typedef __attribute__((ext_vector_type(4))) short bf16x4;
typedef __attribute__((ext_vector_type(4))) float f32x4;

typedef const __attribute__((address_space(1))) unsigned int* gptr_t;
typedef __attribute__((address_space(3))) unsigned int* lptr_t;

static __device__ __forceinline__ short f2bf(float f) {
    __hip_bfloat16 h = __float2bfloat16(f);
    return *reinterpret_cast<short*>(&h);
}

// ---------------- convert: fp32 -> bf16 (x_l, x_s) and transposed bf16 weights ----------------
__global__ void convert_k(const float* __restrict__ xs, const float* __restrict__ xl,
                          const float* __restrict__ Wq, const float* __restrict__ Wk,
                          const float* __restrict__ Wv,
                          short* __restrict__ xl_bf, short* __restrict__ xs_bf,
                          short* __restrict__ WT /* [3][512*512], row=n col=k */) {
    int i = blockIdx.x * blockDim.x + threadIdx.x;   // 0 .. 786431
    if (i < 524288) {
        float4 a = ((const float4*)xl)[i];
        float4 b = ((const float4*)xs)[i];
        short4 oa = make_short4(f2bf(a.x), f2bf(a.y), f2bf(a.z), f2bf(a.w));
        short4 ob = make_short4(f2bf(b.x), f2bf(b.y), f2bf(b.z), f2bf(b.w));
        ((short4*)xl_bf)[i] = oa;
        ((short4*)xs_bf)[i] = ob;
    }
    if (i < 786432) {
        int which = i >> 18;
        int j = i & 262143;
        int n = j >> 9, k = j & 511;
        const float* W = which == 0 ? Wq : (which == 1 ? Wk : Wv);
        WT[i] = f2bf(W[k * 512 + n]);
    }
}

// ---------------- projection GEMM v2: BK=64, swizzled LDS, 768 blocks = 3/CU ----------------
// out[z] = A[z] @ W[z] + b[z].  A [4096][512] bf16, WT [512 n][512 k] bf16, out bf16.
// LDS chunk-swizzle: LDS[row][sub] holds global 16B-chunk (row, sub ^ (row&7));
// achieved by pre-swizzling the per-lane GLOBAL source (global_load_lds dst stays linear).
__global__ __launch_bounds__(256, 3) void proj_gemm(
    const short* __restrict__ xl_bf, const short* __restrict__ xs_bf,
    const short* __restrict__ WT, const float* __restrict__ bq,
    const float* __restrict__ bk, const float* __restrict__ bv,
    short* __restrict__ qkv) {
    __shared__ __attribute__((aligned(16))) short A_lds[128 * 64];   // 16 KB
    __shared__ __attribute__((aligned(16))) short B_lds[64 * 64];    // 8 KB
    const int z = blockIdx.z;
    const int m0 = blockIdx.x * 128;
    const int n0 = blockIdx.y * 64;
    const short* A = (z == 0) ? xl_bf : xs_bf;
    const short* WTz = WT + z * 262144;
    const float* bias = (z == 0) ? bq : ((z == 1) ? bk : bv);
    short* out = qkv + (size_t)z * M_ROWS * CDIM;
    const int t = threadIdx.x, w = t >> 6, lane = t & 63;
    const int lr = lane & 15, g = lane >> 4;

    f32x4 acc[2][4] = {};
    for (int kt = 0; kt < 8; ++kt) {
        const int k0 = kt * 64;
        // A tile [128][64]: 1024 chunks of 16B, 4 rounds
#pragma unroll
        for (int r = 0; r < 4; ++r) {
            int c = r * 256 + t;
            int row = c >> 3, sub = c & 7;
            const short* src = A + (size_t)(m0 + row) * CDIM + k0 + ((sub ^ (row & 7)) * 8);
            __builtin_amdgcn_global_load_lds((gptr_t)src,
                (lptr_t)(A_lds + (r * 256 + w * 64) * 8), 16, 0, 0);
        }
        // B tile [64][64]: 512 chunks, 2 rounds
#pragma unroll
        for (int r = 0; r < 2; ++r) {
            int c = r * 256 + t;
            int row = c >> 3, sub = c & 7;
            const short* src = WTz + (size_t)(n0 + row) * CDIM + k0 + ((sub ^ (row & 7)) * 8);
            __builtin_amdgcn_global_load_lds((gptr_t)src,
                (lptr_t)(B_lds + (r * 256 + w * 64) * 8), 16, 0, 0);
        }
        __syncthreads();
        bf16x8 afr[2][2], bfr[4][2];
#pragma unroll
        for (int mt = 0; mt < 2; ++mt)
#pragma unroll
            for (int kk = 0; kk < 2; ++kk) {
                int row = w * 32 + mt * 16 + lr;
                int slot = (kk * 4 + g) ^ (row & 7);
                afr[mt][kk] = *(const bf16x8*)(A_lds + row * 64 + slot * 8);
            }
#pragma unroll
        for (int nt = 0; nt < 4; ++nt)
#pragma unroll
            for (int kk = 0; kk < 2; ++kk) {
                int row = nt * 16 + lr;
                int slot = (kk * 4 + g) ^ (row & 7);
                bfr[nt][kk] = *(const bf16x8*)(B_lds + row * 64 + slot * 8);
            }
#pragma unroll
        for (int kk = 0; kk < 2; ++kk)
#pragma unroll
            for (int mt = 0; mt < 2; ++mt)
#pragma unroll
                for (int nt = 0; nt < 4; ++nt)
                    acc[mt][nt] = __builtin_amdgcn_mfma_f32_16x16x32_bf16(
                        afr[mt][kk], bfr[nt][kk], acc[mt][nt], 0, 0, 0);
        __syncthreads();
    }
    // epilogue: + bias -> bf16.  C layout: col=lane&15, row=4*(lane>>4)+reg
#pragma unroll
    for (int mt = 0; mt < 2; ++mt) {
#pragma unroll
        for (int nt = 0; nt < 4; ++nt) {
            int col = n0 + nt * 16 + lr;
            float bv_ = bias[col];
            int row0 = m0 + w * 32 + mt * 16 + g * 4;
#pragma unroll
            for (int r = 0; r < 4; ++r)
                out[(size_t)(row0 + r) * CDIM + col] = f2bf(acc[mt][nt][r] + bv_);
        }
    }
}

// ---------------- fused windowed cross-attention v4 ----------------
// 1024 blocks (= exactly 4/CU, XCD-bijective), 4 waves. Block: 64 queries x 32 patches.
// LDS double-buffered K/V^T staging, ONE barrier per patch; T14 split (loads->regs
// before compute, regs->LDS after). Swapped QK^T, zero-shuffle PV, plain f32x4 stores.
__global__ __launch_bounds__(256, 4) void attn_k(
    const short* __restrict__ q_bf, const short* __restrict__ k_bf,
    const short* __restrict__ v_bf, float* __restrict__ out) {
    __shared__ __attribute__((aligned(16))) short k_lds[2][S2 * 64];
    __shared__ __attribute__((aligned(16))) short vT_lds[2][64 * S2];
    const int bid = blockIdx.x;
    const int wid = ((bid & 7) << 7) | (bid >> 3);     // bijective: 1024 % 8 == 0
    const int bh = wid >> 5;
    const int b = bh >> 3, h = bh & 7;
    const int rem = wid & 31;
    const int qtile = rem >> 1, pg = rem & 1;
    const int t = threadIdx.x, w = t >> 6, lane = t & 63;
    const int lr = lane & 15, g = lane >> 4;
    const int l_loc = qtile * 64 + w * 16 + lr;

    // Q fragments (persist): B-operand col=lr, k-slot(g,i) = half*32 + g*8 + i
    bf16x8 qfr[2];
    {
        const short* qrow = q_bf + (size_t)(b * NPX + l_loc) * CDIM + h * HD;
        qfr[0] = *(const bf16x8*)(qrow + g * 8);
        qfr[1] = *(const bf16x8*)(qrow + 32 + g * 8);
    }
    float* outbh = out + (size_t)bh * PS * NPX * HD;
    const int p0 = pg * 32;

    // staging map: thread t covers K-row s, cols c4..c4+3
    const int s = t >> 4, c4 = (t & 15) * 4;
    const int swidx = (s * 64 + c4) ^ ((s & 7) << 3);
    const size_t rowbase = (size_t)(b * NPX) * CDIM + h * HD + c4;
    auto nidx = [&](int p) {
        int py = p >> 3, px = p & 7;
        return py * 128 + (s >> 2) * 32 + px * 4 + (s & 3);
    };
    short4 kreg, vreg;
    {   // prologue: stage patch p0 into buf 0
        int n = nidx(p0);
        kreg = *(const short4*)(k_bf + rowbase + (size_t)n * CDIM);
        vreg = *(const short4*)(v_bf + rowbase + (size_t)n * CDIM);
        *(short4*)(&k_lds[0][swidx]) = kreg;
        vT_lds[0][(c4 + 0) * S2 + s] = vreg.x;
        vT_lds[0][(c4 + 1) * S2 + s] = vreg.y;
        vT_lds[0][(c4 + 2) * S2 + s] = vreg.z;
        vT_lds[0][(c4 + 3) * S2 + s] = vreg.w;
    }
    for (int pi = 0; pi < 32; ++pi) {
        const int buf = pi & 1;
        __syncthreads();                    // buf ready; everyone done reading buf^1
        if (pi < 31) {                      // T14: issue next loads early
            int n = nidx(p0 + pi + 1);
            kreg = *(const short4*)(k_bf + rowbase + (size_t)n * CDIM);
            vreg = *(const short4*)(v_bf + rowbase + (size_t)n * CDIM);
        }
        // K A-frags: row = s = lr, k-slot = half*32 + g*8 + i  (same convention as Q)
        const short* kb = k_lds[buf];
        bf16x8 kfr0 = *(const bf16x8*)(kb + ((lr * 64 + g * 8) ^ ((lr & 7) << 3)));
        bf16x8 kfr1 = *(const bf16x8*)(kb + ((lr * 64 + 32 + g * 8) ^ ((lr & 7) << 3)));
        const short* vb = vT_lds[buf];
        bf16x4 vfr4[4];
#pragma unroll
        for (int dt = 0; dt < 4; ++dt)
            vfr4[dt] = *(const bf16x4*)(vb + (dt * 16 + lr) * S2 + g * 4);

        f32x4 s_acc = {};
        s_acc = __builtin_amdgcn_mfma_f32_16x16x32_bf16(kfr0, qfr[0], s_acc, 0, 0, 0);
        s_acc = __builtin_amdgcn_mfma_f32_16x16x32_bf16(kfr1, qfr[1], s_acc, 0, 0, 0);
        // lane holds S^T[s=4g+r][l=lr]; softmax over 16 s
        float sv[4];
        float m = -1e30f;
#pragma unroll
        for (int r = 0; r < 4; ++r) { sv[r] = s_acc[r] * 0.125f; m = fmaxf(m, sv[r]); }
        m = fmaxf(m, __shfl_xor(m, 16));
        m = fmaxf(m, __shfl_xor(m, 32));
        float pv[4]; float sum = 0.f;
#pragma unroll
        for (int r = 0; r < 4; ++r) { pv[r] = __expf(sv[r] - m); sum += pv[r]; }
        sum += __shfl_xor(sum, 16);
        sum += __shfl_xor(sum, 32);
        float rs = 1.f / sum;
        bf16x8 pfr = { f2bf(pv[0] * rs), f2bf(pv[1] * rs), f2bf(pv[2] * rs), f2bf(pv[3] * rs),
                       0, 0, 0, 0 };
        // PV: out^T[d][l] = sum_s V^T[d][s] * P^T[s][l]
        f32x4 oacc[4];
#pragma unroll
        for (int dt = 0; dt < 4; ++dt) {
            bf16x8 vfr = { vfr4[dt][0], vfr4[dt][1], vfr4[dt][2], vfr4[dt][3], 0, 0, 0, 0 };
            f32x4 zero = {};
            oacc[dt] = __builtin_amdgcn_mfma_f32_16x16x32_bf16(vfr, pfr, zero, 0, 0, 0);
        }
        float* op = outbh + ((size_t)(p0 + pi) * NPX + l_loc) * HD;
#pragma unroll
        for (int dt = 0; dt < 4; ++dt)
            *(f32x4*)(op + dt * 16 + g * 4) = oacc[dt];
        if (pi < 31) {                      // write next patch into other buffer
            *(short4*)(&k_lds[buf ^ 1][swidx]) = kreg;
            vT_lds[buf ^ 1][(c4 + 0) * S2 + s] = vreg.x;
            vT_lds[buf ^ 1][(c4 + 1) * S2 + s] = vreg.y;
            vT_lds[buf ^ 1][(c4 + 2) * S2 + s] = vreg.z;
            vT_lds[buf ^ 1][(c4 + 3) * S2 + s] = vreg.w;
        }
    }
}

extern "C" void kernel_launch(void* const* d_in, const int* in_sizes, int n_in,
                              void* d_out, int out_size, void* d_ws, size_t ws_size,
                              hipStream_t stream) {
    const float* x_s = (const float*)d_in[0];
    const float* x_l = (const float*)d_in[1];
    const float* Wq  = (const float*)d_in[2];
    const float* bq  = (const float*)d_in[3];
    const float* Wk  = (const float*)d_in[4];
    const float* bk  = (const float*)d_in[5];
    const float* Wv  = (const float*)d_in[6];
    const float* bv  = (const float*)d_in[7];
    float* out = (float*)d_out;
    char* ws = (char*)d_ws;

    short* xl_bf = (short*)(ws);                    // 4 MiB
    short* xs_bf = (short*)(ws + 4194304);          // 4 MiB
    short* WT    = (short*)(ws + 8388608);          // 1.5 MiB
    short* qkv   = (short*)(ws + 9961472);          // 12 MiB
    short* q_bf = qkv;
    short* k_bf = qkv + 2097152;
    short* v_bf = qkv + 4194304;

    // MEASUREMENT ROUND: convert & proj launched TWICE (kernels are pure ->
    // output identical); round 7 removes the dup, dur6 - dur7 = convert+proj.
    convert_k<<<3072, 256, 0, stream>>>(x_s, x_l, Wq, Wk, Wv, xl_bf, xs_bf, WT);
    convert_k<<<3072, 256, 0, stream>>>(x_s, x_l, Wq, Wk, Wv, xl_bf, xs_bf, WT);
    proj_gemm<<<dim3(32, 8, 3), 256, 0, stream>>>(xl_bf, xs_bf, WT, bq, bk, bv, qkv);
    proj_gemm<<<dim3(32, 8, 3), 256, 0, stream>>>(xl_bf, xs_bf, WT, bq, bk, bv, qkv);
    attn_k<<<1024, 256, 0, stream>>>(q_bf, k_bf, v_bf, out);
}

// Round 8
// 155.747 us; speedup vs baseline: 1.1913x; 1.0951x over previous
//
#include <hip/hip_runtime.h>
#include <hip/hip_bf16.h>

#define NB 4
#define NH 8
#define NPX 1024
#define HD 64
#define CDIM 512
#define M_ROWS 4096
#define PS 64
#define S2 16

typedef __attribute__((ext_vector_type(8))) short bf16x8;
typedef __attribute__((ext_vector_type(4))) short bf16x4;
typedef __attribute__((ext_vector_type(4))) float f32x4;

typedef const __attribute__((address_space(1))) unsigned int* gptr_t;
typedef __attribute__((address_space(3))) unsigned int* lptr_t;

static __device__ __forceinline__ short f2bf(float f) {
    __hip_bfloat16 h = __float2bfloat16(f);
    return *reinterpret_cast<short*>(&h);
}

// ---------------- convert: fp32 -> bf16 (x_l, x_s) and transposed bf16 weights ----------------
__global__ void convert_k(const float* __restrict__ xs, const float* __restrict__ xl,
                          const float* __restrict__ Wq, const float* __restrict__ Wk,
                          const float* __restrict__ Wv,
                          short* __restrict__ xl_bf, short* __restrict__ xs_bf,
                          short* __restrict__ WT /* [3][512*512], row=n col=k */) {
    int i = blockIdx.x * blockDim.x + threadIdx.x;   // 0 .. 786431
    if (i < 524288) {
        float4 a = ((const float4*)xl)[i];
        float4 b = ((const float4*)xs)[i];
        short4 oa = make_short4(f2bf(a.x), f2bf(a.y), f2bf(a.z), f2bf(a.w));
        short4 ob = make_short4(f2bf(b.x), f2bf(b.y), f2bf(b.z), f2bf(b.w));
        ((short4*)xl_bf)[i] = oa;
        ((short4*)xs_bf)[i] = ob;
    }
    if (i < 786432) {
        int which = i >> 18;
        int j = i & 262143;
        int n = j >> 9, k = j & 511;
        const float* W = which == 0 ? Wq : (which == 1 ? Wk : Wv);
        WT[i] = f2bf(W[k * 512 + n]);
    }
}

// ---------------- projection GEMM v2: BK=64, swizzled LDS, 768 blocks = 3/CU ----------------
// out[z] = A[z] @ W[z] + b[z].  A [4096][512] bf16, WT [512 n][512 k] bf16, out bf16.
// LDS chunk-swizzle: LDS[row][sub] holds global 16B-chunk (row, sub ^ (row&7));
// achieved by pre-swizzling the per-lane GLOBAL source (global_load_lds dst stays linear).
__global__ __launch_bounds__(256, 3) void proj_gemm(
    const short* __restrict__ xl_bf, const short* __restrict__ xs_bf,
    const short* __restrict__ WT, const float* __restrict__ bq,
    const float* __restrict__ bk, const float* __restrict__ bv,
    short* __restrict__ qkv) {
    __shared__ __attribute__((aligned(16))) short A_lds[128 * 64];   // 16 KB
    __shared__ __attribute__((aligned(16))) short B_lds[64 * 64];    // 8 KB
    const int z = blockIdx.z;
    const int m0 = blockIdx.x * 128;
    const int n0 = blockIdx.y * 64;
    const short* A = (z == 0) ? xl_bf : xs_bf;
    const short* WTz = WT + z * 262144;
    const float* bias = (z == 0) ? bq : ((z == 1) ? bk : bv);
    short* out = qkv + (size_t)z * M_ROWS * CDIM;
    const int t = threadIdx.x, w = t >> 6, lane = t & 63;
    const int lr = lane & 15, g = lane >> 4;

    f32x4 acc[2][4] = {};
    for (int kt = 0; kt < 8; ++kt) {
        const int k0 = kt * 64;
        // A tile [128][64]: 1024 chunks of 16B, 4 rounds
#pragma unroll
        for (int r = 0; r < 4; ++r) {
            int c = r * 256 + t;
            int row = c >> 3, sub = c & 7;
            const short* src = A + (size_t)(m0 + row) * CDIM + k0 + ((sub ^ (row & 7)) * 8);
            __builtin_amdgcn_global_load_lds((gptr_t)src,
                (lptr_t)(A_lds + (r * 256 + w * 64) * 8), 16, 0, 0);
        }
        // B tile [64][64]: 512 chunks, 2 rounds
#pragma unroll
        for (int r = 0; r < 2; ++r) {
            int c = r * 256 + t;
            int row = c >> 3, sub = c & 7;
            const short* src = WTz + (size_t)(n0 + row) * CDIM + k0 + ((sub ^ (row & 7)) * 8);
            __builtin_amdgcn_global_load_lds((gptr_t)src,
                (lptr_t)(B_lds + (r * 256 + w * 64) * 8), 16, 0, 0);
        }
        __syncthreads();
        bf16x8 afr[2][2], bfr[4][2];
#pragma unroll
        for (int mt = 0; mt < 2; ++mt)
#pragma unroll
            for (int kk = 0; kk < 2; ++kk) {
                int row = w * 32 + mt * 16 + lr;
                int slot = (kk * 4 + g) ^ (row & 7);
                afr[mt][kk] = *(const bf16x8*)(A_lds + row * 64 + slot * 8);
            }
#pragma unroll
        for (int nt = 0; nt < 4; ++nt)
#pragma unroll
            for (int kk = 0; kk < 2; ++kk) {
                int row = nt * 16 + lr;
                int slot = (kk * 4 + g) ^ (row & 7);
                bfr[nt][kk] = *(const bf16x8*)(B_lds + row * 64 + slot * 8);
            }
#pragma unroll
        for (int kk = 0; kk < 2; ++kk)
#pragma unroll
            for (int mt = 0; mt < 2; ++mt)
#pragma unroll
                for (int nt = 0; nt < 4; ++nt)
                    acc[mt][nt] = __builtin_amdgcn_mfma_f32_16x16x32_bf16(
                        afr[mt][kk], bfr[nt][kk], acc[mt][nt], 0, 0, 0);
        __syncthreads();
    }
    // epilogue: + bias -> bf16.  C layout: col=lane&15, row=4*(lane>>4)+reg
#pragma unroll
    for (int mt = 0; mt < 2; ++mt) {
#pragma unroll
        for (int nt = 0; nt < 4; ++nt) {
            int col = n0 + nt * 16 + lr;
            float bv_ = bias[col];
            int row0 = m0 + w * 32 + mt * 16 + g * 4;
#pragma unroll
            for (int r = 0; r < 4; ++r)
                out[(size_t)(row0 + r) * CDIM + col] = f2bf(acc[mt][nt][r] + bv_);
        }
    }
}

// ---------------- fused windowed cross-attention v4 ----------------
// 1024 blocks (= exactly 4/CU, XCD-bijective), 4 waves. Block: 64 queries x 32 patches.
// LDS double-buffered K/V^T staging, ONE barrier per patch; T14 split (loads->regs
// before compute, regs->LDS after). Swapped QK^T, zero-shuffle PV, plain f32x4 stores.
__global__ __launch_bounds__(256, 4) void attn_k(
    const short* __restrict__ q_bf, const short* __restrict__ k_bf,
    const short* __restrict__ v_bf, float* __restrict__ out) {
    __shared__ __attribute__((aligned(16))) short k_lds[2][S2 * 64];
    __shared__ __attribute__((aligned(16))) short vT_lds[2][64 * S2];
    const int bid = blockIdx.x;
    const int wid = ((bid & 7) << 7) | (bid >> 3);     // bijective: 1024 % 8 == 0
    const int bh = wid >> 5;
    const int b = bh >> 3, h = bh & 7;
    const int rem = wid & 31;
    const int qtile = rem >> 1, pg = rem & 1;
    const int t = threadIdx.x, w = t >> 6, lane = t & 63;
    const int lr = lane & 15, g = lane >> 4;
    const int l_loc = qtile * 64 + w * 16 + lr;

    // Q fragments (persist): B-operand col=lr, k-slot(g,i) = half*32 + g*8 + i
    bf16x8 qfr[2];
    {
        const short* qrow = q_bf + (size_t)(b * NPX + l_loc) * CDIM + h * HD;
        qfr[0] = *(const bf16x8*)(qrow + g * 8);
        qfr[1] = *(const bf16x8*)(qrow + 32 + g * 8);
    }
    float* outbh = out + (size_t)bh * PS * NPX * HD;
    const int p0 = pg * 32;

    // staging map: thread t covers K-row s, cols c4..c4+3
    const int s = t >> 4, c4 = (t & 15) * 4;
    const int swidx = (s * 64 + c4) ^ ((s & 7) << 3);
    const size_t rowbase = (size_t)(b * NPX) * CDIM + h * HD + c4;
    auto nidx = [&](int p) {
        int py = p >> 3, px = p & 7;
        return py * 128 + (s >> 2) * 32 + px * 4 + (s & 3);
    };
    short4 kreg, vreg;
    {   // prologue: stage patch p0 into buf 0
        int n = nidx(p0);
        kreg = *(const short4*)(k_bf + rowbase + (size_t)n * CDIM);
        vreg = *(const short4*)(v_bf + rowbase + (size_t)n * CDIM);
        *(short4*)(&k_lds[0][swidx]) = kreg;
        vT_lds[0][(c4 + 0) * S2 + s] = vreg.x;
        vT_lds[0][(c4 + 1) * S2 + s] = vreg.y;
        vT_lds[0][(c4 + 2) * S2 + s] = vreg.z;
        vT_lds[0][(c4 + 3) * S2 + s] = vreg.w;
    }
    for (int pi = 0; pi < 32; ++pi) {
        const int buf = pi & 1;
        __syncthreads();                    // buf ready; everyone done reading buf^1
        if (pi < 31) {                      // T14: issue next loads early
            int n = nidx(p0 + pi + 1);
            kreg = *(const short4*)(k_bf + rowbase + (size_t)n * CDIM);
            vreg = *(const short4*)(v_bf + rowbase + (size_t)n * CDIM);
        }
        // K A-frags: row = s = lr, k-slot = half*32 + g*8 + i  (same convention as Q)
        const short* kb = k_lds[buf];
        bf16x8 kfr0 = *(const bf16x8*)(kb + ((lr * 64 + g * 8) ^ ((lr & 7) << 3)));
        bf16x8 kfr1 = *(const bf16x8*)(kb + ((lr * 64 + 32 + g * 8) ^ ((lr & 7) << 3)));
        const short* vb = vT_lds[buf];
        bf16x4 vfr4[4];
#pragma unroll
        for (int dt = 0; dt < 4; ++dt)
            vfr4[dt] = *(const bf16x4*)(vb + (dt * 16 + lr) * S2 + g * 4);

        f32x4 s_acc = {};
        s_acc = __builtin_amdgcn_mfma_f32_16x16x32_bf16(kfr0, qfr[0], s_acc, 0, 0, 0);
        s_acc = __builtin_amdgcn_mfma_f32_16x16x32_bf16(kfr1, qfr[1], s_acc, 0, 0, 0);
        // lane holds S^T[s=4g+r][l=lr]; softmax over 16 s
        float sv[4];
        float m = -1e30f;
#pragma unroll
        for (int r = 0; r < 4; ++r) { sv[r] = s_acc[r] * 0.125f; m = fmaxf(m, sv[r]); }
        m = fmaxf(m, __shfl_xor(m, 16));
        m = fmaxf(m, __shfl_xor(m, 32));
        float pv[4]; float sum = 0.f;
#pragma unroll
        for (int r = 0; r < 4; ++r) { pv[r] = __expf(sv[r] - m); sum += pv[r]; }
        sum += __shfl_xor(sum, 16);
        sum += __shfl_xor(sum, 32);
        float rs = 1.f / sum;
        bf16x8 pfr = { f2bf(pv[0] * rs), f2bf(pv[1] * rs), f2bf(pv[2] * rs), f2bf(pv[3] * rs),
                       0, 0, 0, 0 };
        // PV: out^T[d][l] = sum_s V^T[d][s] * P^T[s][l]
        f32x4 oacc[4];
#pragma unroll
        for (int dt = 0; dt < 4; ++dt) {
            bf16x8 vfr = { vfr4[dt][0], vfr4[dt][1], vfr4[dt][2], vfr4[dt][3], 0, 0, 0, 0 };
            f32x4 zero = {};
            oacc[dt] = __builtin_amdgcn_mfma_f32_16x16x32_bf16(vfr, pfr, zero, 0, 0, 0);
        }
        float* op = outbh + ((size_t)(p0 + pi) * NPX + l_loc) * HD;
#pragma unroll
        for (int dt = 0; dt < 4; ++dt)
            *(f32x4*)(op + dt * 16 + g * 4) = oacc[dt];
        if (pi < 31) {                      // write next patch into other buffer
            *(short4*)(&k_lds[buf ^ 1][swidx]) = kreg;
            vT_lds[buf ^ 1][(c4 + 0) * S2 + s] = vreg.x;
            vT_lds[buf ^ 1][(c4 + 1) * S2 + s] = vreg.y;
            vT_lds[buf ^ 1][(c4 + 2) * S2 + s] = vreg.z;
            vT_lds[buf ^ 1][(c4 + 3) * S2 + s] = vreg.w;
        }
    }
}

extern "C" void kernel_launch(void* const* d_in, const int* in_sizes, int n_in,
                              void* d_out, int out_size, void* d_ws, size_t ws_size,
                              hipStream_t stream) {
    const float* x_s = (const float*)d_in[0];
    const float* x_l = (const float*)d_in[1];
    const float* Wq  = (const float*)d_in[2];
    const float* bq  = (const float*)d_in[3];
    const float* Wk  = (const float*)d_in[4];
    const float* bk  = (const float*)d_in[5];
    const float* Wv  = (const float*)d_in[6];
    const float* bv  = (const float*)d_in[7];
    float* out = (float*)d_out;
    char* ws = (char*)d_ws;

    short* xl_bf = (short*)(ws);                    // 4 MiB
    short* xs_bf = (short*)(ws + 4194304);          // 4 MiB
    short* WT    = (short*)(ws + 8388608);          // 1.5 MiB
    short* qkv   = (short*)(ws + 9961472);          // 12 MiB
    short* q_bf = qkv;
    short* k_bf = qkv + 2097152;
    short* v_bf = qkv + 4194304;

    // Single-launch round: dur7(dup) - dur8(this) = one convert+proj pass.
    convert_k<<<3072, 256, 0, stream>>>(x_s, x_l, Wq, Wk, Wv, xl_bf, xs_bf, WT);
    proj_gemm<<<dim3(32, 8, 3), 256, 0, stream>>>(xl_bf, xs_bf, WT, bq, bk, bv, qkv);
    attn_k<<<1024, 256, 0, stream>>>(q_bf, k_bf, v_bf, out);
}

// Round 9
// 152.971 us; speedup vs baseline: 1.2129x; 1.0181x over previous
//
#include <hip/hip_runtime.h>
#include <hip/hip_bf16.h>

#define NB 4
#define NH 8
#define NPX 1024
#define HD 64
#define CDIM 512
#define M_ROWS 4096
#define PS 64
#define S2 16

typedef __attribute__((ext_vector_type(8))) short bf16x8;
typedef __attribute__((ext_vector_type(4))) short bf16x4;
typedef __attribute__((ext_vector_type(4))) float f32x4;

typedef const __attribute__((address_space(1))) unsigned int* gptr_t;
typedef __attribute__((address_space(3))) unsigned int* lptr_t;

static __device__ __forceinline__ short f2bf(float f) {
    __hip_bfloat16 h = __float2bfloat16(f);
    return *reinterpret_cast<short*>(&h);
}

// ---------------- convert: fp32 -> bf16 (x_l, x_s) and transposed bf16 weights ----------------
__global__ void convert_k(const float* __restrict__ xs, const float* __restrict__ xl,
                          const float* __restrict__ Wq, const float* __restrict__ Wk,
                          const float* __restrict__ Wv,
                          short* __restrict__ xl_bf, short* __restrict__ xs_bf,
                          short* __restrict__ WT /* [3][512*512], row=n col=k */) {
    int i = blockIdx.x * blockDim.x + threadIdx.x;   // 0 .. 786431
    if (i < 524288) {
        float4 a = ((const float4*)xl)[i];
        float4 b = ((const float4*)xs)[i];
        short4 oa = make_short4(f2bf(a.x), f2bf(a.y), f2bf(a.z), f2bf(a.w));
        short4 ob = make_short4(f2bf(b.x), f2bf(b.y), f2bf(b.z), f2bf(b.w));
        ((short4*)xl_bf)[i] = oa;
        ((short4*)xs_bf)[i] = ob;
    }
    if (i < 786432) {
        int which = i >> 18;
        int j = i & 262143;
        int n = j >> 9, k = j & 511;
        const float* W = which == 0 ? Wq : (which == 1 ? Wk : Wv);
        WT[i] = f2bf(W[k * 512 + n]);
    }
}

// ---------------- projection GEMM v2: BK=64, swizzled LDS, 768 blocks = 3/CU ----------------
__global__ __launch_bounds__(256, 3) void proj_gemm(
    const short* __restrict__ xl_bf, const short* __restrict__ xs_bf,
    const short* __restrict__ WT, const float* __restrict__ bq,
    const float* __restrict__ bk, const float* __restrict__ bv,
    short* __restrict__ qkv) {
    __shared__ __attribute__((aligned(16))) short A_lds[128 * 64];   // 16 KB
    __shared__ __attribute__((aligned(16))) short B_lds[64 * 64];    // 8 KB
    const int z = blockIdx.z;
    const int m0 = blockIdx.x * 128;
    const int n0 = blockIdx.y * 64;
    const short* A = (z == 0) ? xl_bf : xs_bf;
    const short* WTz = WT + z * 262144;
    const float* bias = (z == 0) ? bq : ((z == 1) ? bk : bv);
    short* out = qkv + (size_t)z * M_ROWS * CDIM;
    const int t = threadIdx.x, w = t >> 6, lane = t & 63;
    const int lr = lane & 15, g = lane >> 4;

    f32x4 acc[2][4] = {};
    for (int kt = 0; kt < 8; ++kt) {
        const int k0 = kt * 64;
#pragma unroll
        for (int r = 0; r < 4; ++r) {
            int c = r * 256 + t;
            int row = c >> 3, sub = c & 7;
            const short* src = A + (size_t)(m0 + row) * CDIM + k0 + ((sub ^ (row & 7)) * 8);
            __builtin_amdgcn_global_load_lds((gptr_t)src,
                (lptr_t)(A_lds + (r * 256 + w * 64) * 8), 16, 0, 0);
        }
#pragma unroll
        for (int r = 0; r < 2; ++r) {
            int c = r * 256 + t;
            int row = c >> 3, sub = c & 7;
            const short* src = WTz + (size_t)(n0 + row) * CDIM + k0 + ((sub ^ (row & 7)) * 8);
            __builtin_amdgcn_global_load_lds((gptr_t)src,
                (lptr_t)(B_lds + (r * 256 + w * 64) * 8), 16, 0, 0);
        }
        __syncthreads();
        bf16x8 afr[2][2], bfr[4][2];
#pragma unroll
        for (int mt = 0; mt < 2; ++mt)
#pragma unroll
            for (int kk = 0; kk < 2; ++kk) {
                int row = w * 32 + mt * 16 + lr;
                int slot = (kk * 4 + g) ^ (row & 7);
                afr[mt][kk] = *(const bf16x8*)(A_lds + row * 64 + slot * 8);
            }
#pragma unroll
        for (int nt = 0; nt < 4; ++nt)
#pragma unroll
            for (int kk = 0; kk < 2; ++kk) {
                int row = nt * 16 + lr;
                int slot = (kk * 4 + g) ^ (row & 7);
                bfr[nt][kk] = *(const bf16x8*)(B_lds + row * 64 + slot * 8);
            }
#pragma unroll
        for (int kk = 0; kk < 2; ++kk)
#pragma unroll
            for (int mt = 0; mt < 2; ++mt)
#pragma unroll
                for (int nt = 0; nt < 4; ++nt)
                    acc[mt][nt] = __builtin_amdgcn_mfma_f32_16x16x32_bf16(
                        afr[mt][kk], bfr[nt][kk], acc[mt][nt], 0, 0, 0);
        __syncthreads();
    }
#pragma unroll
    for (int mt = 0; mt < 2; ++mt) {
#pragma unroll
        for (int nt = 0; nt < 4; ++nt) {
            int col = n0 + nt * 16 + lr;
            float bv_ = bias[col];
            int row0 = m0 + w * 32 + mt * 16 + g * 4;
#pragma unroll
            for (int r = 0; r < 4; ++r)
                out[(size_t)(row0 + r) * CDIM + col] = f2bf(acc[mt][nt][r] + bv_);
        }
    }
}

// ---------------- fused windowed cross-attention v5 ----------------
// 1024 blocks (4/CU, XCD-bijective), 4 waves, 64 queries x 32 patches per block.
// 2 patches per barrier phase (16 phases). Raw s_barrier + lgkmcnt(0) ONLY —
// output stores are never drained in-loop (no vmcnt(0)). Double-buffered LDS.
__global__ __launch_bounds__(256, 4) void attn_k(
    const short* __restrict__ q_bf, const short* __restrict__ k_bf,
    const short* __restrict__ v_bf, float* __restrict__ out) {
    __shared__ __attribute__((aligned(16))) short k_lds[2][2][S2 * 64];
    __shared__ __attribute__((aligned(16))) short vT_lds[2][2][64 * S2];
    const int bid = blockIdx.x;
    const int wid = ((bid & 7) << 7) | (bid >> 3);     // bijective: 1024 % 8 == 0
    const int bh = wid >> 5;
    const int b = bh >> 3, h = bh & 7;
    const int rem = wid & 31;
    const int qtile = rem >> 1, pg = rem & 1;
    const int t = threadIdx.x, w = t >> 6, lane = t & 63;
    const int lr = lane & 15, g = lane >> 4;
    const int l_loc = qtile * 64 + w * 16 + lr;

    // Q fragments (persist): B-operand col=lr, k-slot(g,i) = half*32 + g*8 + i
    bf16x8 qfr[2];
    {
        const short* qrow = q_bf + (size_t)(b * NPX + l_loc) * CDIM + h * HD;
        qfr[0] = *(const bf16x8*)(qrow + g * 8);
        qfr[1] = *(const bf16x8*)(qrow + 32 + g * 8);
    }
    float* outbh = out + (size_t)bh * PS * NPX * HD;
    const int p0 = pg * 32;

    // staging map: thread t covers K-row s, cols c4..c4+3
    const int s = t >> 4, c4 = (t & 15) * 4;
    const int swidx = (s * 64 + c4) ^ ((s & 7) << 3);
    const size_t rowbase = (size_t)(b * NPX) * CDIM + h * HD + c4;
    auto nidx = [&](int p) {
        int py = p >> 3, px = p & 7;
        return py * 128 + (s >> 2) * 32 + px * 4 + (s & 3);
    };
    short4 kreg[2], vreg[2];
    auto loadg = [&](int gi) {
#pragma unroll
        for (int pp = 0; pp < 2; ++pp) {
            int n = nidx(p0 + gi * 2 + pp);
            kreg[pp] = *(const short4*)(k_bf + rowbase + (size_t)n * CDIM);
            vreg[pp] = *(const short4*)(v_bf + rowbase + (size_t)n * CDIM);
        }
    };
    auto writeg = [&](int buf) {
#pragma unroll
        for (int pp = 0; pp < 2; ++pp) {
            *(short4*)(&k_lds[buf][pp][swidx]) = kreg[pp];
            vT_lds[buf][pp][(c4 + 0) * S2 + s] = vreg[pp].x;
            vT_lds[buf][pp][(c4 + 1) * S2 + s] = vreg[pp].y;
            vT_lds[buf][pp][(c4 + 2) * S2 + s] = vreg[pp].z;
            vT_lds[buf][pp][(c4 + 3) * S2 + s] = vreg[pp].w;
        }
    };
    loadg(0);
    writeg(0);
    for (int si = 0; si < 16; ++si) {
        const int buf = si & 1;
        // barrier WITHOUT store drain: only LDS ops must be visible
        asm volatile("s_waitcnt lgkmcnt(0)" ::: "memory");
        __builtin_amdgcn_s_barrier();
        __builtin_amdgcn_sched_barrier(0);
        if (si < 15) loadg(si + 1);          // T14: issue next loads early
#pragma unroll
        for (int pp = 0; pp < 2; ++pp) {
            const short* kb = k_lds[buf][pp];
            bf16x8 kfr0 = *(const bf16x8*)(kb + ((lr * 64 + g * 8) ^ ((lr & 7) << 3)));
            bf16x8 kfr1 = *(const bf16x8*)(kb + ((lr * 64 + 32 + g * 8) ^ ((lr & 7) << 3)));
            const short* vb = vT_lds[buf][pp];
            bf16x4 vfr4[4];
#pragma unroll
            for (int dt = 0; dt < 4; ++dt)
                vfr4[dt] = *(const bf16x4*)(vb + (dt * 16 + lr) * S2 + g * 4);

            f32x4 s_acc = {};
            s_acc = __builtin_amdgcn_mfma_f32_16x16x32_bf16(kfr0, qfr[0], s_acc, 0, 0, 0);
            s_acc = __builtin_amdgcn_mfma_f32_16x16x32_bf16(kfr1, qfr[1], s_acc, 0, 0, 0);
            // lane holds S^T[s=4g+r][l=lr]; softmax over 16 s
            float sv[4];
            float m = -1e30f;
#pragma unroll
            for (int r = 0; r < 4; ++r) { sv[r] = s_acc[r] * 0.125f; m = fmaxf(m, sv[r]); }
            m = fmaxf(m, __shfl_xor(m, 16));
            m = fmaxf(m, __shfl_xor(m, 32));
            float pv[4]; float sum = 0.f;
#pragma unroll
            for (int r = 0; r < 4; ++r) { pv[r] = __expf(sv[r] - m); sum += pv[r]; }
            sum += __shfl_xor(sum, 16);
            sum += __shfl_xor(sum, 32);
            float rs = 1.f / sum;
            bf16x8 pfr = { f2bf(pv[0] * rs), f2bf(pv[1] * rs), f2bf(pv[2] * rs), f2bf(pv[3] * rs),
                           0, 0, 0, 0 };
            // PV: out^T[d][l] = sum_s V^T[d][s] * P^T[s][l]
            f32x4 oacc[4];
#pragma unroll
            for (int dt = 0; dt < 4; ++dt) {
                bf16x8 vfr = { vfr4[dt][0], vfr4[dt][1], vfr4[dt][2], vfr4[dt][3], 0, 0, 0, 0 };
                f32x4 zero = {};
                oacc[dt] = __builtin_amdgcn_mfma_f32_16x16x32_bf16(vfr, pfr, zero, 0, 0, 0);
            }
            float* op = outbh + ((size_t)(p0 + si * 2 + pp) * NPX + l_loc) * HD;
#pragma unroll
            for (int dt = 0; dt < 4; ++dt)
                *(f32x4*)(op + dt * 16 + g * 4) = oacc[dt];
        }
        if (si < 15) writeg(buf ^ 1);        // stage next pair into other buffer
    }
}

extern "C" void kernel_launch(void* const* d_in, const int* in_sizes, int n_in,
                              void* d_out, int out_size, void* d_ws, size_t ws_size,
                              hipStream_t stream) {
    const float* x_s = (const float*)d_in[0];
    const float* x_l = (const float*)d_in[1];
    const float* Wq  = (const float*)d_in[2];
    const float* bq  = (const float*)d_in[3];
    const float* Wk  = (const float*)d_in[4];
    const float* bk  = (const float*)d_in[5];
    const float* Wv  = (const float*)d_in[6];
    const float* bv  = (const float*)d_in[7];
    float* out = (float*)d_out;
    char* ws = (char*)d_ws;

    short* xl_bf = (short*)(ws);                    // 4 MiB
    short* xs_bf = (short*)(ws + 4194304);          // 4 MiB
    short* WT    = (short*)(ws + 8388608);          // 1.5 MiB
    short* qkv   = (short*)(ws + 9961472);          // 12 MiB
    short* q_bf = qkv;
    short* k_bf = qkv + 2097152;
    short* v_bf = qkv + 4194304;

    convert_k<<<3072, 256, 0, stream>>>(x_s, x_l, Wq, Wk, Wv, xl_bf, xs_bf, WT);
    proj_gemm<<<dim3(32, 8, 3), 256, 0, stream>>>(xl_bf, xs_bf, WT, bq, bk, bv, qkv);
    attn_k<<<1024, 256, 0, stream>>>(q_bf, k_bf, v_bf, out);
}

// Round 10
// 131.879 us; speedup vs baseline: 1.4069x; 1.1599x over previous
//
#include <hip/hip_runtime.h>
#include <hip/hip_bf16.h>

#define NB 4
#define NH 8
#define NPX 1024
#define HD 64
#define CDIM 512
#define M_ROWS 4096
#define PS 64
#define S2 16

typedef __attribute__((ext_vector_type(8))) short bf16x8;
typedef __attribute__((ext_vector_type(4))) short bf16x4;
typedef __attribute__((ext_vector_type(4))) float f32x4;

typedef const __attribute__((address_space(1))) unsigned int* gptr_t;
typedef __attribute__((address_space(3))) unsigned int* lptr_t;

static __device__ __forceinline__ short f2bf(float f) {
    __hip_bfloat16 h = __float2bfloat16(f);
    return *reinterpret_cast<short*>(&h);
}

// ---------------- convert: fp32 -> bf16 (x_l, x_s) and transposed bf16 weights ----------------
__global__ void convert_k(const float* __restrict__ xs, const float* __restrict__ xl,
                          const float* __restrict__ Wq, const float* __restrict__ Wk,
                          const float* __restrict__ Wv,
                          short* __restrict__ xl_bf, short* __restrict__ xs_bf,
                          short* __restrict__ WT /* [3][512*512], row=n col=k */) {
    int i = blockIdx.x * blockDim.x + threadIdx.x;   // 0 .. 786431
    if (i < 524288) {
        float4 a = ((const float4*)xl)[i];
        float4 b = ((const float4*)xs)[i];
        short4 oa = make_short4(f2bf(a.x), f2bf(a.y), f2bf(a.z), f2bf(a.w));
        short4 ob = make_short4(f2bf(b.x), f2bf(b.y), f2bf(b.z), f2bf(b.w));
        ((short4*)xl_bf)[i] = oa;
        ((short4*)xs_bf)[i] = ob;
    }
    if (i < 786432) {
        int which = i >> 18;
        int j = i & 262143;
        int n = j >> 9, k = j & 511;
        const float* W = which == 0 ? Wq : (which == 1 ? Wk : Wv);
        WT[i] = f2bf(W[k * 512 + n]);
    }
}

// ---------------- projection GEMM v2: BK=64, swizzled LDS, 768 blocks = 3/CU ----------------
__global__ __launch_bounds__(256, 3) void proj_gemm(
    const short* __restrict__ xl_bf, const short* __restrict__ xs_bf,
    const short* __restrict__ WT, const float* __restrict__ bq,
    const float* __restrict__ bk, const float* __restrict__ bv,
    short* __restrict__ qkv) {
    __shared__ __attribute__((aligned(16))) short A_lds[128 * 64];   // 16 KB
    __shared__ __attribute__((aligned(16))) short B_lds[64 * 64];    // 8 KB
    const int z = blockIdx.z;
    const int m0 = blockIdx.x * 128;
    const int n0 = blockIdx.y * 64;
    const short* A = (z == 0) ? xl_bf : xs_bf;
    const short* WTz = WT + z * 262144;
    const float* bias = (z == 0) ? bq : ((z == 1) ? bk : bv);
    short* out = qkv + (size_t)z * M_ROWS * CDIM;
    const int t = threadIdx.x, w = t >> 6, lane = t & 63;
    const int lr = lane & 15, g = lane >> 4;

    f32x4 acc[2][4] = {};
    for (int kt = 0; kt < 8; ++kt) {
        const int k0 = kt * 64;
#pragma unroll
        for (int r = 0; r < 4; ++r) {
            int c = r * 256 + t;
            int row = c >> 3, sub = c & 7;
            const short* src = A + (size_t)(m0 + row) * CDIM + k0 + ((sub ^ (row & 7)) * 8);
            __builtin_amdgcn_global_load_lds((gptr_t)src,
                (lptr_t)(A_lds + (r * 256 + w * 64) * 8), 16, 0, 0);
        }
#pragma unroll
        for (int r = 0; r < 2; ++r) {
            int c = r * 256 + t;
            int row = c >> 3, sub = c & 7;
            const short* src = WTz + (size_t)(n0 + row) * CDIM + k0 + ((sub ^ (row & 7)) * 8);
            __builtin_amdgcn_global_load_lds((gptr_t)src,
                (lptr_t)(B_lds + (r * 256 + w * 64) * 8), 16, 0, 0);
        }
        __syncthreads();
        bf16x8 afr[2][2], bfr[4][2];
#pragma unroll
        for (int mt = 0; mt < 2; ++mt)
#pragma unroll
            for (int kk = 0; kk < 2; ++kk) {
                int row = w * 32 + mt * 16 + lr;
                int slot = (kk * 4 + g) ^ (row & 7);
                afr[mt][kk] = *(const bf16x8*)(A_lds + row * 64 + slot * 8);
            }
#pragma unroll
        for (int nt = 0; nt < 4; ++nt)
#pragma unroll
            for (int kk = 0; kk < 2; ++kk) {
                int row = nt * 16 + lr;
                int slot = (kk * 4 + g) ^ (row & 7);
                bfr[nt][kk] = *(const bf16x8*)(B_lds + row * 64 + slot * 8);
            }
#pragma unroll
        for (int kk = 0; kk < 2; ++kk)
#pragma unroll
            for (int mt = 0; mt < 2; ++mt)
#pragma unroll
                for (int nt = 0; nt < 4; ++nt)
                    acc[mt][nt] = __builtin_amdgcn_mfma_f32_16x16x32_bf16(
                        afr[mt][kk], bfr[nt][kk], acc[mt][nt], 0, 0, 0);
        __syncthreads();
    }
#pragma unroll
    for (int mt = 0; mt < 2; ++mt) {
#pragma unroll
        for (int nt = 0; nt < 4; ++nt) {
            int col = n0 + nt * 16 + lr;
            float bv_ = bias[col];
            int row0 = m0 + w * 32 + mt * 16 + g * 4;
#pragma unroll
            for (int r = 0; r < 4; ++r)
                out[(size_t)(row0 + r) * CDIM + col] = f2bf(acc[mt][nt][r] + bv_);
        }
    }
}

// ---------------- fused windowed cross-attention v6 ----------------
// v5 + contiguous-store path: oacc -> per-wave LDS transpose -> 4x 1KB-contiguous
// global stores per patch (was 4x strided 16x64B half-line stores).
__global__ __launch_bounds__(256, 4) void attn_k(
    const short* __restrict__ q_bf, const short* __restrict__ k_bf,
    const short* __restrict__ v_bf, float* __restrict__ out) {
    __shared__ __attribute__((aligned(16))) short k_lds[2][2][S2 * 64];
    __shared__ __attribute__((aligned(16))) short vT_lds[2][2][64 * S2];
    __shared__ __attribute__((aligned(16))) float st_lds[4 * 16 * 68];   // per-wave 16x68
    const int bid = blockIdx.x;
    const int wid = ((bid & 7) << 7) | (bid >> 3);     // bijective: 1024 % 8 == 0
    const int bh = wid >> 5;
    const int b = bh >> 3, h = bh & 7;
    const int rem = wid & 31;
    const int qtile = rem >> 1, pg = rem & 1;
    const int t = threadIdx.x, w = t >> 6, lane = t & 63;
    const int lr = lane & 15, g = lane >> 4;
    const int l_loc = qtile * 64 + w * 16 + lr;

    // Q fragments (persist): B-operand col=lr, k-slot(g,i) = half*32 + g*8 + i
    bf16x8 qfr[2];
    {
        const short* qrow = q_bf + (size_t)(b * NPX + l_loc) * CDIM + h * HD;
        qfr[0] = *(const bf16x8*)(qrow + g * 8);
        qfr[1] = *(const bf16x8*)(qrow + 32 + g * 8);
    }
    float* outbh = out + (size_t)bh * PS * NPX * HD;
    const int p0 = pg * 32;
    float* stw = st_lds + w * 1088;
    const int srow = lane >> 4, schunk = lane & 15;

    // staging map: thread t covers K-row s, cols c4..c4+3
    const int s = t >> 4, c4 = (t & 15) * 4;
    const int swidx = (s * 64 + c4) ^ ((s & 7) << 3);
    const size_t rowbase = (size_t)(b * NPX) * CDIM + h * HD + c4;
    auto nidx = [&](int p) {
        int py = p >> 3, px = p & 7;
        return py * 128 + (s >> 2) * 32 + px * 4 + (s & 3);
    };
    short4 kreg[2], vreg[2];
    auto loadg = [&](int gi) {
#pragma unroll
        for (int pp = 0; pp < 2; ++pp) {
            int n = nidx(p0 + gi * 2 + pp);
            kreg[pp] = *(const short4*)(k_bf + rowbase + (size_t)n * CDIM);
            vreg[pp] = *(const short4*)(v_bf + rowbase + (size_t)n * CDIM);
        }
    };
    auto writeg = [&](int buf) {
#pragma unroll
        for (int pp = 0; pp < 2; ++pp) {
            *(short4*)(&k_lds[buf][pp][swidx]) = kreg[pp];
            vT_lds[buf][pp][(c4 + 0) * S2 + s] = vreg[pp].x;
            vT_lds[buf][pp][(c4 + 1) * S2 + s] = vreg[pp].y;
            vT_lds[buf][pp][(c4 + 2) * S2 + s] = vreg[pp].z;
            vT_lds[buf][pp][(c4 + 3) * S2 + s] = vreg[pp].w;
        }
    };
    loadg(0);
    writeg(0);
    for (int si = 0; si < 16; ++si) {
        const int buf = si & 1;
        // barrier WITHOUT store drain: only LDS ops must be visible
        asm volatile("s_waitcnt lgkmcnt(0)" ::: "memory");
        __builtin_amdgcn_s_barrier();
        __builtin_amdgcn_sched_barrier(0);
        if (si < 15) loadg(si + 1);          // T14: issue next loads early
#pragma unroll
        for (int pp = 0; pp < 2; ++pp) {
            const short* kb = k_lds[buf][pp];
            bf16x8 kfr0 = *(const bf16x8*)(kb + ((lr * 64 + g * 8) ^ ((lr & 7) << 3)));
            bf16x8 kfr1 = *(const bf16x8*)(kb + ((lr * 64 + 32 + g * 8) ^ ((lr & 7) << 3)));
            const short* vb = vT_lds[buf][pp];
            bf16x4 vfr4[4];
#pragma unroll
            for (int dt = 0; dt < 4; ++dt)
                vfr4[dt] = *(const bf16x4*)(vb + (dt * 16 + lr) * S2 + g * 4);

            f32x4 s_acc = {};
            s_acc = __builtin_amdgcn_mfma_f32_16x16x32_bf16(kfr0, qfr[0], s_acc, 0, 0, 0);
            s_acc = __builtin_amdgcn_mfma_f32_16x16x32_bf16(kfr1, qfr[1], s_acc, 0, 0, 0);
            // lane holds S^T[s=4g+r][l=lr]; softmax over 16 s
            float sv[4];
            float m = -1e30f;
#pragma unroll
            for (int r = 0; r < 4; ++r) { sv[r] = s_acc[r] * 0.125f; m = fmaxf(m, sv[r]); }
            m = fmaxf(m, __shfl_xor(m, 16));
            m = fmaxf(m, __shfl_xor(m, 32));
            float pv[4]; float sum = 0.f;
#pragma unroll
            for (int r = 0; r < 4; ++r) { pv[r] = __expf(sv[r] - m); sum += pv[r]; }
            sum += __shfl_xor(sum, 16);
            sum += __shfl_xor(sum, 32);
            float rs = 1.f / sum;
            bf16x8 pfr = { f2bf(pv[0] * rs), f2bf(pv[1] * rs), f2bf(pv[2] * rs), f2bf(pv[3] * rs),
                           0, 0, 0, 0 };
            // PV: out^T[d][l] = sum_s V^T[d][s] * P^T[s][l]
            f32x4 oacc[4];
#pragma unroll
            for (int dt = 0; dt < 4; ++dt) {
                bf16x8 vfr = { vfr4[dt][0], vfr4[dt][1], vfr4[dt][2], vfr4[dt][3], 0, 0, 0, 0 };
                f32x4 zero = {};
                oacc[dt] = __builtin_amdgcn_mfma_f32_16x16x32_bf16(vfr, pfr, zero, 0, 0, 0);
            }
            // ---- contiguous-store path: per-wave LDS transpose ----
            // write: lane(lr,g) row=lr, cols dt*16+g*4 ; wave-local, no barrier
#pragma unroll
            for (int dt = 0; dt < 4; ++dt)
                *(f32x4*)(stw + lr * 68 + dt * 16 + g * 4) = oacc[dt];
            // read back: lane i -> row 4u+(i>>4), chunk (i&15); 4x 1KB contiguous stores
            float* opbase = outbh + ((size_t)(p0 + si * 2 + pp) * NPX + qtile * 64 + w * 16) * HD;
#pragma unroll
            for (int u = 0; u < 4; ++u) {
                f32x4 vout = *(const f32x4*)(stw + (u * 4 + srow) * 68 + schunk * 4);
                *(f32x4*)(opbase + (size_t)(u * 4 + srow) * HD + schunk * 4) = vout;
            }
        }
        if (si < 15) writeg(buf ^ 1);        // stage next pair into other buffer
    }
}

extern "C" void kernel_launch(void* const* d_in, const int* in_sizes, int n_in,
                              void* d_out, int out_size, void* d_ws, size_t ws_size,
                              hipStream_t stream) {
    const float* x_s = (const float*)d_in[0];
    const float* x_l = (const float*)d_in[1];
    const float* Wq  = (const float*)d_in[2];
    const float* bq  = (const float*)d_in[3];
    const float* Wk  = (const float*)d_in[4];
    const float* bk  = (const float*)d_in[5];
    const float* Wv  = (const float*)d_in[6];
    const float* bv  = (const float*)d_in[7];
    float* out = (float*)d_out;
    char* ws = (char*)d_ws;

    short* xl_bf = (short*)(ws);                    // 4 MiB
    short* xs_bf = (short*)(ws + 4194304);          // 4 MiB
    short* WT    = (short*)(ws + 8388608);          // 1.5 MiB
    short* qkv   = (short*)(ws + 9961472);          // 12 MiB
    short* q_bf = qkv;
    short* k_bf = qkv + 2097152;
    short* v_bf = qkv + 4194304;

    convert_k<<<3072, 256, 0, stream>>>(x_s, x_l, Wq, Wk, Wv, xl_bf, xs_bf, WT);
    proj_gemm<<<dim3(32, 8, 3), 256, 0, stream>>>(xl_bf, xs_bf, WT, bq, bk, bv, qkv);
    attn_k<<<1024, 256, 0, stream>>>(q_bf, k_bf, v_bf, out);
}